// Round 9
// baseline (134.247 us; speedup 1.0000x reference)
//
#include <hip/hip_runtime.h>

// Problem constants
#define MM 15   // max_peptide_size
#define RR 64   // aa_rep_size
#define PP 34   // pocket positions
#define FF 9    // filter size
#define AA 20   // alphabet size
#define OW 72   // RR + FF - 1
#define KS 12   // kernels row stride (floats), 16B-aligned
#define AJ 20   // adj-float row stride (16B-aligned, rows hit distinct bank groups)
#define AJROWS 48  // 34 real rows + 14 zero rows so p=q+32 needs no branch

__global__ __launch_bounds__(256)
void ppc_kernel(const float* __restrict__ pe,      // [B, M, R]
                const int*   __restrict__ idx,     // [B, P]
                const int*   __restrict__ adj,     // [B, P, M]
                const float* __restrict__ kernels, // [A, F]
                float*       __restrict__ out)     // [B, P, OW]
{
    const int b = blockIdx.x;
    const int t = threadIdx.x;

    __shared__ float s_pe[MM * RR];        // 960 f
    __shared__ float s_kern[AA * KS];      // 240 f
    __shared__ float s_adjf[AJROWS * AJ];  // 960 f (cols 15..19 and rows >=34 zero)
    __shared__ int   s_idx[PP];

    const float* peb  = pe  + (size_t)b * (MM * RR);
    const int*   adjb = adj + (size_t)b * (PP * MM);

    // ---- staging (coalesced); zero s_adjf first, then fill real entries
    for (int i = t; i < AJROWS * AJ; i += 256) s_adjf[i] = 0.0f;
    if (t < (MM * RR) / 4)
        *(float4*)&s_pe[t * 4] = *(const float4*)&peb[t * 4];
    if (t < AA * FF) {
        int a = (unsigned)t / FF, j = t - a * FF;
        s_kern[a * KS + j] = kernels[t];
    }
    if (t < PP) s_idx[t] = idx[(size_t)b * PP + t];
    __syncthreads();   // s_adjf zeros must land before fills
    for (int i = t; i < PP * MM; i += 256) {
        int p = (unsigned)i / MM, m = i - p * MM;
        s_adjf[p * AJ + m] = (float)adjb[i];
    }
    __syncthreads();

    const int c  = t & 15;   // r-quad within row
    const int q  = t >> 4;   // 0..15; handles p = q, q+16, q+32
    const int r0 = c << 2;

    // ---- Phase B (registers): S_k = s[p_k][r0..r0+3], adj rows read as float4 chunks
    float4 S0, S1, S2;
    {
        const float* g0 = &s_adjf[(q)      * AJ];
        const float* g1 = &s_adjf[(q + 16) * AJ];
        const float* g2 = &s_adjf[(q + 32) * AJ];
        float x0=0,y0=0,z0=0,w0=0, x1=0,y1=0,z1=0,w1=0, x2=0,y2=0,z2=0,w2=0;
        #pragma unroll
        for (int mc = 0; mc < 4; ++mc) {
            const float4 a0 = *(const float4*)&g0[mc * 4];
            const float4 a1 = *(const float4*)&g1[mc * 4];
            const float4 a2 = *(const float4*)&g2[mc * 4];
            #pragma unroll
            for (int mm = 0; mm < 4; ++mm) {
                const int m = mc * 4 + mm;
                if (m < MM) {   // compile-time after unroll
                    const float4 v = *(const float4*)&s_pe[m * RR + r0]; // broadcast
                    const float ga = (&a0.x)[mm], gb = (&a1.x)[mm], gc = (&a2.x)[mm];
                    x0 += ga*v.x; y0 += ga*v.y; z0 += ga*v.z; w0 += ga*v.w;
                    x1 += gb*v.x; y1 += gb*v.y; z1 += gb*v.z; w1 += gb*v.w;
                    x2 += gc*v.x; y2 += gc*v.y; z2 += gc*v.z; w2 += gc*v.w;
                }
            }
        }
        S0 = make_float4(x0,y0,z0,w0);
        S1 = make_float4(x1,y1,z1,w1);
        S2 = make_float4(x2,y2,z2,w2);
    }

    float* outb = out + (size_t)b * (PP * OW);

    // ---- Phase C: conv in registers; neighbor quads via wave shuffles
    auto conv_p = [&](const float4 S, const int p) {
        float kf[FF];
        {
            const int a = (p < PP) ? s_idx[p] : 0;
            const float* kb = &s_kern[a * KS];      // 16B-aligned, broadcast
            const float4 k0 = *(const float4*)&kb[0];
            const float4 k1 = *(const float4*)&kb[4];
            kf[0]=k0.x; kf[1]=k0.y; kf[2]=k0.z; kf[3]=k0.w;
            kf[4]=k1.x; kf[5]=k1.y; kf[6]=k1.z; kf[7]=k1.w;
            kf[8]=kb[8];
        }
        float4 SM1, SM2, SP1;
        SM1.x=__shfl_up(S.x,1); SM1.y=__shfl_up(S.y,1); SM1.z=__shfl_up(S.z,1); SM1.w=__shfl_up(S.w,1);
        SM2.x=__shfl_up(S.x,2); SM2.y=__shfl_up(S.y,2); SM2.z=__shfl_up(S.z,2); SM2.w=__shfl_up(S.w,2);
        SP1.x=__shfl_down(S.x,1); SP1.y=__shfl_down(S.y,1); SP1.z=__shfl_down(S.z,1); SP1.w=__shfl_down(S.w,1);
        if (c < 1) SM1 = make_float4(0,0,0,0);
        if (c < 2) SM2 = make_float4(0,0,0,0);

        float w[12];
        w[0]=SM2.x; w[1]=SM2.y; w[2] =SM2.z; w[3] =SM2.w;
        w[4]=SM1.x; w[5]=SM1.y; w[6] =SM1.z; w[7] =SM1.w;
        w[8]=S.x;   w[9]=S.y;   w[10]=S.z;   w[11]=S.w;

        float ax=0, ay=0, az=0, aw=0;
        #pragma unroll
        for (int j = 0; j < FF; ++j) {
            const float k = kf[j];
            ax += k * w[8  - j];
            ay += k * w[9  - j];
            az += k * w[10 - j];
            aw += k * w[11 - j];
        }
        if (p < PP)
            *(float4*)&outb[p * OW + r0] = make_float4(ax, ay, az, aw);

        // tail quads: o0=64 (c==14, window = [S | SP1 | 0]) and o0=68 (c==15, [S | 0 | 0])
        if (c >= 14 && p < PP) {
            float wt[12];
            wt[0]=S.x; wt[1]=S.y; wt[2]=S.z; wt[3]=S.w;
            if (c == 14) { wt[4]=SP1.x; wt[5]=SP1.y; wt[6]=SP1.z; wt[7]=SP1.w; }
            else         { wt[4]=0;     wt[5]=0;     wt[6]=0;     wt[7]=0;     }
            wt[8]=0; wt[9]=0; wt[10]=0; wt[11]=0;
            float tx=0, ty=0, tz=0, tw=0;
            #pragma unroll
            for (int j = 0; j < FF; ++j) {
                const float k = kf[j];
                tx += k * wt[8  - j];
                ty += k * wt[9  - j];
                tz += k * wt[10 - j];
                tw += k * wt[11 - j];
            }
            const int o0 = (c == 14) ? 64 : 68;
            *(float4*)&outb[p * OW + o0] = make_float4(tx, ty, tz, tw);
        }
    };

    conv_p(S0, q);
    conv_p(S1, q + 16);
    conv_p(S2, q + 32);
}

extern "C" void kernel_launch(void* const* d_in, const int* in_sizes, int n_in,
                              void* d_out, int out_size, void* d_ws, size_t ws_size,
                              hipStream_t stream) {
    const float* pe      = (const float*)d_in[0]; // [B,M,R] f32
    const int*   idx     = (const int*)  d_in[1]; // [B,P]   i32
    const int*   adj     = (const int*)  d_in[2]; // [B,P,M] i32
    const float* kernels = (const float*)d_in[3]; // [A,F]   f32
    float*       out     = (float*)d_out;

    const int B = in_sizes[0] / (MM * RR);
    ppc_kernel<<<B, 256, 0, stream>>>(pe, idx, adj, kernels, out);
}

// Round 10
// 72.006 us; speedup vs baseline: 1.8644x; 1.8644x over previous
//
#include <hip/hip_runtime.h>

// Problem constants
#define MM 15   // max_peptide_size
#define RR 64   // aa_rep_size
#define PP 34   // pocket positions
#define FF 9    // filter size
#define AA 20   // alphabet size
#define OW 72   // RR + FF - 1
#define SP 84   // s_s row stride (floats), 16B-aligned (336B)
#define KS 12   // kernels row stride (floats), 16B-aligned
#define AJ 20   // adj-float row stride (floats), 16B-aligned
#define AJROWS 48  // 34 real rows + 14 zero rows (p=q+32 branch-free in Phase B)

__global__ __launch_bounds__(256)
void ppc_kernel(const float* __restrict__ pe,      // [B, M, R]
                const int*   __restrict__ idx,     // [B, P]
                const int*   __restrict__ adj,     // [B, P, M]
                const float* __restrict__ kernels, // [A, F]
                float*       __restrict__ out)     // [B, P, OW]
{
    const int b = blockIdx.x;
    const int t = threadIdx.x;

    __shared__ float s_pe[MM * RR];        // 960 f
    __shared__ float s_kern[AA * KS];      // 240 f
    __shared__ float s_adjf[AJROWS * AJ];  // 960 f (cols 15..19, rows>=34 zeroed)
    __shared__ int   s_idx[PP];
    __shared__ float s_s[PP * SP];         // 2856 f, zero-padded conv rows

    const float* peb  = pe  + (size_t)b * (MM * RR);
    const int*   adjb = adj + (size_t)b * (PP * MM);

    // ---- staging (one barrier total; adj fills/pads are disjoint regions)
    if (t < (MM * RR) / 4)
        *(float4*)&s_pe[t * 4] = *(const float4*)&peb[t * 4];
    if (t < AA * FF) {
        int a = (unsigned)t / FF, j = t - a * FF;
        s_kern[a * KS + j] = kernels[t];
    }
    for (int i = t; i < PP * MM; i += 256) {          // real adj entries
        int p = (unsigned)i / MM, m = i - p * MM;
        s_adjf[p * AJ + m] = (float)adjb[i];
    }
    for (int i = t; i < PP * 5; i += 256) {           // pad cols 15..19, rows 0..33
        int p = (unsigned)i / 5, k = i - p * 5;
        s_adjf[p * AJ + MM + k] = 0.0f;
    }
    for (int i = t; i < (AJROWS - PP) * AJ; i += 256) // pad rows 34..47
        s_adjf[PP * AJ + i] = 0.0f;
    if (t < PP) s_idx[t] = idx[(size_t)b * PP + t];
    for (int i = t; i < PP * 20; i += 256) {          // s_s conv zero pads
        int p = (unsigned)i / 20, c2 = i - p * 20;
        s_s[p * SP + (c2 < 8 ? c2 : 64 + c2)] = 0.0f;
    }
    __syncthreads();

    const int c  = t & 15;   // r-quad within row
    const int q  = t >> 4;   // q-group owns p = q, q+16, q+32
    const int r0 = c << 2;

    // ---- Phase B: s[p][r0..r0+3] for 3 p's; pe reads broadcast across q-groups
    {
        const float* g0 = &s_adjf[(q)      * AJ];
        const float* g1 = &s_adjf[(q + 16) * AJ];
        const float* g2 = &s_adjf[(q + 32) * AJ];   // zero row if q+32 >= 34
        float x0=0,y0=0,z0=0,w0=0, x1=0,y1=0,z1=0,w1=0, x2=0,y2=0,z2=0,w2=0;
        #pragma unroll
        for (int mc = 0; mc < 4; ++mc) {
            const float4 a0 = *(const float4*)&g0[mc * 4];
            const float4 a1 = *(const float4*)&g1[mc * 4];
            const float4 a2 = *(const float4*)&g2[mc * 4];
            #pragma unroll
            for (int mm = 0; mm < 4; ++mm) {
                const int m = mc * 4 + mm;
                if (m < MM) {   // compile-time after unroll
                    const float4 v = *(const float4*)&s_pe[m * RR + r0];
                    const float ga = (&a0.x)[mm], gb = (&a1.x)[mm], gc = (&a2.x)[mm];
                    x0 += ga*v.x; y0 += ga*v.y; z0 += ga*v.z; w0 += ga*v.w;
                    x1 += gb*v.x; y1 += gb*v.y; z1 += gb*v.z; w1 += gb*v.w;
                    x2 += gc*v.x; y2 += gc*v.y; z2 += gc*v.z; w2 += gc*v.w;
                }
            }
        }
        *(float4*)&s_s[(q)      * SP + 8 + r0] = make_float4(x0,y0,z0,w0);
        *(float4*)&s_s[(q + 16) * SP + 8 + r0] = make_float4(x1,y1,z1,w1);
        if (q + 32 < PP)
            *(float4*)&s_s[(q + 32) * SP + 8 + r0] = make_float4(x2,y2,z2,w2);
    }
    __syncthreads();

    float* outb = out + (size_t)b * (PP * OW);

    // ---- Phase C: lane c -> o0 = 4c (c<2 also o0 = 64+4c); aligned b128 reads
    auto do_p = [&](const int p) {
        float kf[FF];
        {
            const float* kb = &s_kern[s_idx[p] * KS];   // group-uniform broadcast
            const float4 k0 = *(const float4*)&kb[0];
            const float4 k1 = *(const float4*)&kb[4];
            kf[0]=k0.x; kf[1]=k0.y; kf[2]=k0.z; kf[3]=k0.w;
            kf[4]=k1.x; kf[5]=k1.y; kf[6]=k1.z; kf[7]=k1.w;
            kf[8]=kb[8];
        }
        const float* row = &s_s[p * SP];
        {
            float w[12];
            *(float4*)&w[0] = *(const float4*)&row[r0];      // s[p][r0-8..]
            *(float4*)&w[4] = *(const float4*)&row[r0 + 4];
            *(float4*)&w[8] = *(const float4*)&row[r0 + 8];
            float ax=0, ay=0, az=0, aw=0;
            #pragma unroll
            for (int j = 0; j < FF; ++j) {
                const float k = kf[j];
                ax += k * w[8  - j];
                ay += k * w[9  - j];
                az += k * w[10 - j];
                aw += k * w[11 - j];
            }
            *(float4*)&outb[p * OW + r0] = make_float4(ax, ay, az, aw);
        }
        if (c < 2) {                      // tail quads o0 = 64, 68
            const int o0 = 64 + r0;
            float w[12];
            *(float4*)&w[0] = *(const float4*)&row[o0];
            *(float4*)&w[4] = *(const float4*)&row[o0 + 4];
            *(float4*)&w[8] = *(const float4*)&row[o0 + 8];
            float ax=0, ay=0, az=0, aw=0;
            #pragma unroll
            for (int j = 0; j < FF; ++j) {
                const float k = kf[j];
                ax += k * w[8  - j];
                ay += k * w[9  - j];
                az += k * w[10 - j];
                aw += k * w[11 - j];
            }
            *(float4*)&outb[p * OW + o0] = make_float4(ax, ay, az, aw);
        }
    };

    do_p(q);
    do_p(q + 16);
    if (q + 32 < PP) do_p(q + 32);
}

extern "C" void kernel_launch(void* const* d_in, const int* in_sizes, int n_in,
                              void* d_out, int out_size, void* d_ws, size_t ws_size,
                              hipStream_t stream) {
    const float* pe      = (const float*)d_in[0]; // [B,M,R] f32
    const int*   idx     = (const int*)  d_in[1]; // [B,P]   i32
    const int*   adj     = (const int*)  d_in[2]; // [B,P,M] i32
    const float* kernels = (const float*)d_in[3]; // [A,F]   f32
    float*       out     = (float*)d_out;

    const int B = in_sizes[0] / (MM * RR);
    ppc_kernel<<<B, 256, 0, stream>>>(pe, idx, adj, kernels, out);
}